// Round 7
// baseline (469.283 us; speedup 1.0000x reference)
//
#include <hip/hip_runtime.h>

#define DFEAT 128
#define CAP   32       // per-node bucket = 2 cache lines; overflow -> spill list
#define SPILLMAX 4096  // expected spill ~tens of edges (Poisson(16) tail past 32)

// ---------------- bucket build: cnt[dst]++, buf[dst][pos] = src ----------------
// CAP=32 so same-dst edge writes share 64B lines (write-combining in L2);
// overflow edges recorded exactly in spill list (no drops).
__global__ __launch_bounds__(256) void bucket_kernel(const int* __restrict__ ei,
                                                     int* __restrict__ cnt,
                                                     int* __restrict__ buf,
                                                     int2* __restrict__ spill,
                                                     int* __restrict__ spillcnt,
                                                     int E) {
    int e = blockIdx.x * 256 + threadIdx.x;
    if (e >= E) return;
    int src = ei[e];
    int dst = ei[E + e];
    int pos = atomicAdd(&cnt[dst], 1);
    if (pos < CAP) {
        buf[dst * CAP + pos] = src;
    } else {
        int sp = atomicAdd(spillcnt, 1);
        if (sp < SPILLMAX) spill[sp] = make_int2(dst, src);
    }
}

// ---------------- dinv[i] = rsqrt(deg) with deg = in-count + 1 (self loop) ----
__global__ __launch_bounds__(256) void dinv_kernel(const int* __restrict__ cnt,
                                                   float* __restrict__ dinv, int n) {
    int i = blockIdx.x * 256 + threadIdx.x;
    if (i < n) dinv[i] = rsqrtf((float)(cnt[i] + 1));
}

// ---------------- GEMM1: h[r][c] = dinv[r] * sum_k x[r][k] W[k][c] -----------
// Block 512 = 8 waves, 128 rows/block. W (64 KB) in LDS unpadded; reads use the
// split-column trick (cols {tx*4, 64+tx*4}) -> 2-way bank aliasing only (free,
// m136). A (x rows) streamed from global: 16 tx-lanes share an address -> merged.
__global__ __launch_bounds__(512) void gemm1_kernel(const float* __restrict__ x,
                                                    const float* __restrict__ W,
                                                    const float* __restrict__ dinv,
                                                    float* __restrict__ h, int n) {
    __shared__ float Wl[DFEAT * DFEAT];
    int tid = threadIdx.x;
#pragma unroll
    for (int it = 0; it < 8; ++it) {
        int idx = tid * 4 + it * 2048;
        *(float4*)(&Wl[idx]) = *(const float4*)(W + idx);
    }
    __syncthreads();

    int ty = tid >> 4;            // 0..31 -> row group of 4
    int tx = tid & 15;            // 0..15 -> col groups
    int row0 = blockIdx.x * 128 + ty * 4;
    int c0a = tx * 4, c0b = 64 + tx * 4;

    int rr[4];
#pragma unroll
    for (int i = 0; i < 4; i++) { int r = row0 + i; rr[i] = (r < n) ? r : (n - 1); }

    float acc[4][8];
#pragma unroll
    for (int i = 0; i < 4; i++)
#pragma unroll
        for (int j = 0; j < 8; j++) acc[i][j] = 0.f;

    for (int k = 0; k < DFEAT; k += 4) {
        float4 a[4];
#pragma unroll
        for (int i = 0; i < 4; i++)
            a[i] = *(const float4*)(x + (size_t)rr[i] * DFEAT + k);
#pragma unroll
        for (int kk = 0; kk < 4; kk++) {
            float4 w0 = *(const float4*)(&Wl[(k + kk) * DFEAT + c0a]);
            float4 w1 = *(const float4*)(&Wl[(k + kk) * DFEAT + c0b]);
#pragma unroll
            for (int i = 0; i < 4; i++) {
                float av = (kk == 0) ? a[i].x : (kk == 1) ? a[i].y : (kk == 2) ? a[i].z : a[i].w;
                acc[i][0] = fmaf(av, w0.x, acc[i][0]);
                acc[i][1] = fmaf(av, w0.y, acc[i][1]);
                acc[i][2] = fmaf(av, w0.z, acc[i][2]);
                acc[i][3] = fmaf(av, w0.w, acc[i][3]);
                acc[i][4] = fmaf(av, w1.x, acc[i][4]);
                acc[i][5] = fmaf(av, w1.y, acc[i][5]);
                acc[i][6] = fmaf(av, w1.z, acc[i][6]);
                acc[i][7] = fmaf(av, w1.w, acc[i][7]);
            }
        }
    }
#pragma unroll
    for (int i = 0; i < 4; i++) {
        int r = row0 + i;
        if (r < n) {
            float s = dinv[r];
            float4 o0 = make_float4(acc[i][0] * s, acc[i][1] * s, acc[i][2] * s, acc[i][3] * s);
            float4 o1 = make_float4(acc[i][4] * s, acc[i][5] * s, acc[i][6] * s, acc[i][7] * s);
            *(float4*)(h + (size_t)r * DFEAT + c0a) = o0;
            *(float4*)(h + (size_t)r * DFEAT + c0b) = o1;
        }
    }
}

// ---------------- propagate: agg[i] = dinv[i]*(h'[i] + sum_src h'[src]) ------
// One wave per node; lane owns float2 of the 128-wide row. Src indices are
// pre-loaded one per lane, then shfl-broadcast -> inner loop is one coalesced
// 512B row gather + 2 adds per edge. Unrolled x8: 8 independent 8B loads in
// flight per lane (h' is L2/L3-resident).
__global__ __launch_bounds__(256) void propagate_kernel(const float* __restrict__ h,
                                                        const int* __restrict__ buf,
                                                        const int* __restrict__ cnt,
                                                        const float* __restrict__ dinv,
                                                        float* __restrict__ agg, int n) {
    int wave = (blockIdx.x * 256 + threadIdx.x) >> 6;
    int lane = threadIdx.x & 63;
    if (wave >= n) return;

    int c = cnt[wave];
    if (c > CAP) c = CAP;
    float di = dinv[wave];

    int mysrc = 0;
    if (lane < c) mysrc = buf[wave * CAP + lane];

    const float2* h2 = (const float2*)h;
    float2 acc = h2[(size_t)wave * 64 + lane];   // self term: h'[self]

    int k = 0;
    for (; k + 7 < c; k += 8) {
        int s[8];
#pragma unroll
        for (int j = 0; j < 8; j++) s[j] = __shfl(mysrc, k + j);
        float2 v[8];
#pragma unroll
        for (int j = 0; j < 8; j++) v[j] = h2[(size_t)s[j] * 64 + lane];
        float sx = ((v[0].x + v[1].x) + (v[2].x + v[3].x)) +
                   ((v[4].x + v[5].x) + (v[6].x + v[7].x));
        float sy = ((v[0].y + v[1].y) + (v[2].y + v[3].y)) +
                   ((v[4].y + v[5].y) + (v[6].y + v[7].y));
        acc.x += sx;
        acc.y += sy;
    }
    for (; k < c; k++) {
        int sidx = __shfl(mysrc, k);
        float2 v = h2[(size_t)sidx * 64 + lane];
        acc.x += v.x;
        acc.y += v.y;
    }
    acc.x *= di;
    acc.y *= di;
    ((float2*)agg)[(size_t)wave * 64 + lane] = acc;
}

// ---------------- spill fix-up: agg[dst] += h'[src] * dinv[dst] --------------
// Handles the ~tens of edges whose dst exceeded CAP. One wave per spill edge;
// runs after propagate (so agg is populated), before gemm2.
__global__ __launch_bounds__(256) void spill_kernel(const float* __restrict__ h,
                                                    const int2* __restrict__ spill,
                                                    const int* __restrict__ spillcnt,
                                                    const float* __restrict__ dinv,
                                                    float* __restrict__ agg) {
    int w = (blockIdx.x * 256 + threadIdx.x) >> 6;
    int lane = threadIdx.x & 63;
    int sc = *spillcnt;
    if (sc > SPILLMAX) sc = SPILLMAX;
    if (w >= sc) return;
    int2 e = spill[w];               // (dst, src)
    float di = dinv[e.x];
    const float2* h2 = (const float2*)h;
    float2 v = h2[(size_t)e.y * 64 + lane];
    atomicAdd(&agg[(size_t)e.x * DFEAT + 2 * lane],     v.x * di);
    atomicAdd(&agg[(size_t)e.x * DFEAT + 2 * lane + 1], v.y * di);
}

// ---------------- GEMM2: out = relu( relu(agg+b) @ Wln^T + x ) ---------------
// Wln staged TRANSPOSED into LDS with XOR swizzle (kills transpose-read
// conflicts). agg (= d_out) streamed in-place: each thread reads only its own
// 4 rows before writing them -> safe without a barrier.
__device__ __forceinline__ int swz(int k, int c) { return c ^ (((k >> 2) & 7) << 2); }

__global__ __launch_bounds__(512) void gemm2_kernel(const float* __restrict__ agg,
                                                    const float* __restrict__ Wln,
                                                    const float* __restrict__ bias,
                                                    const float* __restrict__ x,
                                                    float* __restrict__ out, int n) {
    __shared__ float Wl[DFEAT * DFEAT];
    int tid = threadIdx.x;
#pragma unroll
    for (int it = 0; it < 8; ++it) {
        int idx = tid * 4 + it * 2048;
        float4 v = *(const float4*)(Wln + idx);
        int o  = idx >> 7;    // W_ln row = output col
        int ii = idx & 127;   // W_ln col = k index
        Wl[(ii + 0) * DFEAT + swz(ii + 0, o)] = v.x;
        Wl[(ii + 1) * DFEAT + swz(ii + 1, o)] = v.y;
        Wl[(ii + 2) * DFEAT + swz(ii + 2, o)] = v.z;
        Wl[(ii + 3) * DFEAT + swz(ii + 3, o)] = v.w;
    }
    __syncthreads();

    int ty = tid >> 4;
    int tx = tid & 15;
    int row0 = blockIdx.x * 128 + ty * 4;
    int c0a = tx * 4, c0b = 64 + tx * 4;

    int rr[4];
#pragma unroll
    for (int i = 0; i < 4; i++) { int r = row0 + i; rr[i] = (r < n) ? r : (n - 1); }

    float acc[4][8];
#pragma unroll
    for (int i = 0; i < 4; i++)
#pragma unroll
        for (int j = 0; j < 8; j++) acc[i][j] = 0.f;

    for (int k = 0; k < DFEAT; k += 4) {
        float4 bv = *(const float4*)(bias + k);
        float4 a[4];
#pragma unroll
        for (int i = 0; i < 4; i++) {
            float4 v = *(const float4*)(agg + (size_t)rr[i] * DFEAT + k);
            v.x = fmaxf(v.x + bv.x, 0.f);
            v.y = fmaxf(v.y + bv.y, 0.f);
            v.z = fmaxf(v.z + bv.z, 0.f);
            v.w = fmaxf(v.w + bv.w, 0.f);
            a[i] = v;
        }
#pragma unroll
        for (int kk = 0; kk < 4; kk++) {
            int krow = k + kk;
            float4 w0 = *(const float4*)(&Wl[krow * DFEAT + swz(krow, c0a)]);
            float4 w1 = *(const float4*)(&Wl[krow * DFEAT + swz(krow, c0b)]);
#pragma unroll
            for (int i = 0; i < 4; i++) {
                float av = (kk == 0) ? a[i].x : (kk == 1) ? a[i].y : (kk == 2) ? a[i].z : a[i].w;
                acc[i][0] = fmaf(av, w0.x, acc[i][0]);
                acc[i][1] = fmaf(av, w0.y, acc[i][1]);
                acc[i][2] = fmaf(av, w0.z, acc[i][2]);
                acc[i][3] = fmaf(av, w0.w, acc[i][3]);
                acc[i][4] = fmaf(av, w1.x, acc[i][4]);
                acc[i][5] = fmaf(av, w1.y, acc[i][5]);
                acc[i][6] = fmaf(av, w1.z, acc[i][6]);
                acc[i][7] = fmaf(av, w1.w, acc[i][7]);
            }
        }
    }
#pragma unroll
    for (int i = 0; i < 4; i++) {
        int r = row0 + i;
        if (r < n) {
            float4 x0 = *(const float4*)(x + (size_t)r * DFEAT + c0a);
            float4 x1 = *(const float4*)(x + (size_t)r * DFEAT + c0b);
            float4 o0 = make_float4(fmaxf(acc[i][0] + x0.x, 0.f), fmaxf(acc[i][1] + x0.y, 0.f),
                                    fmaxf(acc[i][2] + x0.z, 0.f), fmaxf(acc[i][3] + x0.w, 0.f));
            float4 o1 = make_float4(fmaxf(acc[i][4] + x1.x, 0.f), fmaxf(acc[i][5] + x1.y, 0.f),
                                    fmaxf(acc[i][6] + x1.z, 0.f), fmaxf(acc[i][7] + x1.w, 0.f));
            *(float4*)(out + (size_t)r * DFEAT + c0a) = o0;
            *(float4*)(out + (size_t)r * DFEAT + c0b) = o1;
        }
    }
}

extern "C" void kernel_launch(void* const* d_in, const int* in_sizes, int n_in,
                              void* d_out, int out_size, void* d_ws, size_t ws_size,
                              hipStream_t stream) {
    const float* x    = (const float*)d_in[0];
    const int*   ei   = (const int*)d_in[1];
    const float* Wg   = (const float*)d_in[2];
    const float* bg   = (const float*)d_in[3];
    const float* Wln  = (const float*)d_in[4];
    float*       out  = (float*)d_out;

    int n = in_sizes[0] / DFEAT;   // 100000
    int E = in_sizes[1] / 2;       // 1600000

    // workspace layout (256B-aligned): cnt | spillcnt | dinv | spill | buf | h
    size_t off = 0;
    auto take = [&](size_t bytes) {
        void* p = (char*)d_ws + off;
        off += (bytes + 255) & ~(size_t)255;
        return p;
    };
    int*   cnt   = (int*)take((size_t)n * 4);
    int*   spc   = (int*)take(256);
    float* dinv  = (float*)take((size_t)n * 4);
    int2*  spill = (int2*)take((size_t)SPILLMAX * 8);
    int*   buf   = (int*)take((size_t)n * CAP * 4);
    float* h     = (float*)take((size_t)n * DFEAT * 4);

    hipMemsetAsync(cnt, 0, (size_t)n * 4, stream);
    hipMemsetAsync(spc, 0, 4, stream);
    bucket_kernel<<<(E + 255) / 256, 256, 0, stream>>>(ei, cnt, buf, spill, spc, E);
    dinv_kernel<<<(n + 255) / 256, 256, 0, stream>>>(cnt, dinv, n);
    gemm1_kernel<<<(n + 127) / 128, 512, 0, stream>>>(x, Wg, dinv, h, n);
    propagate_kernel<<<(n + 3) / 4, 256, 0, stream>>>(h, buf, cnt, dinv, out, n);
    spill_kernel<<<SPILLMAX / 4, 256, 0, stream>>>(h, spill, spc, dinv, out);
    gemm2_kernel<<<(n + 127) / 128, 512, 0, stream>>>(out, Wln, bg, x, out, n);
}

// Round 9
// 384.100 us; speedup vs baseline: 1.2218x; 1.2218x over previous
//
#include <hip/hip_runtime.h>

#define DFEAT 128
#define CAP   32        // per-node bucket entries; overflow -> exact spill list
#define PSH   9         // partition shift: 512 nodes/partition
#define PNODES (1 << PSH)
#define PMAX  1024      // supports n up to 512K nodes
#define REGCAP 10240    // records/partition region (mean E*512/n=8163, >20 sigma)
#define SPILLMAX 4096
#define CHUNK 4096      // edges per block in pass A

// ---------------- pass A: partition edges by dst>>9 into per-partition regions
// LDS histogram -> 1 global atomic per (block,partition) -> contiguous runs of
// 4B packed records ((dst&511)<<23 | src; n<2^23). Full-line friendly writes.
__global__ __launch_bounds__(256) void partA_kernel(const int* __restrict__ ei,
                                                    unsigned* __restrict__ rec,
                                                    int* __restrict__ gcur,
                                                    int2* __restrict__ spill,
                                                    int* __restrict__ spillcnt,
                                                    int E) {
    __shared__ int lhist[PMAX];
    int tid  = threadIdx.x;
    int base = blockIdx.x * CHUNK;
    int end  = min(base + CHUNK, E);
    for (int i = tid; i < PMAX; i += 256) lhist[i] = 0;
    __syncthreads();
    for (int e = base + tid; e < end; e += 256) {
        int dst = ei[E + e];
        atomicAdd(&lhist[dst >> PSH], 1);
    }
    __syncthreads();
    for (int p = tid; p < PMAX; p += 256) {
        int c = lhist[p];
        if (c > 0) lhist[p] = atomicAdd(&gcur[p], c);   // count -> global base
    }
    __syncthreads();
    for (int e = base + tid; e < end; e += 256) {
        int src = ei[e];
        int dst = ei[E + e];
        int p   = dst >> PSH;
        int off = atomicAdd(&lhist[p], 1);              // absolute offset in region
        if (off < REGCAP) {
            rec[(size_t)p * REGCAP + off] =
                ((unsigned)(dst & (PNODES - 1)) << 23) | (unsigned)src;
        } else {                                        // astronomically rare
            int sp = atomicAdd(spillcnt, 1);
            if (sp < SPILLMAX) spill[sp] = make_int2(dst, src);
        }
    }
}

// ---------------- pass B: per-partition bucket build entirely in LDS ---------
// Reads the partition's contiguous records, bins into LDS buckets, then writes
// buckets + cnt + dinv SEQUENTIALLY (full-line streaming stores).
__global__ __launch_bounds__(256) void partB_kernel(const unsigned* __restrict__ rec,
                                                    const int* __restrict__ gcur,
                                                    int* __restrict__ buf,
                                                    int* __restrict__ cnt,
                                                    float* __restrict__ dinv,
                                                    int2* __restrict__ spill,
                                                    int* __restrict__ spillcnt,
                                                    int n) {
    __shared__ int lcnt[PNODES];
    __shared__ int lbuf[PNODES * CAP];                  // 64 KB
    int tid   = threadIdx.x;
    int p     = blockIdx.x;
    int node0 = p << PSH;
    for (int i = tid; i < PNODES; i += 256) lcnt[i] = 0;
    __syncthreads();
    int total = gcur[p];
    if (total > REGCAP) total = REGCAP;
    const unsigned* r = rec + (size_t)p * REGCAP;
    for (int i = tid; i < total; i += 256) {
        unsigned v = r[i];
        int ldst = (int)(v >> 23);
        int src  = (int)(v & 0x7FFFFFu);
        int pos  = atomicAdd(&lcnt[ldst], 1);           // true in-degree counter
        if (pos < CAP) lbuf[(ldst << 5) + pos] = src;
        else {
            int sp = atomicAdd(spillcnt, 1);
            if (sp < SPILLMAX) spill[sp] = make_int2(node0 + ldst, src);
        }
    }
    __syncthreads();
    int nn = min(PNODES, n - node0);
    if (nn <= 0) return;
    int vecs = (nn * CAP) >> 2;                         // nn*32 divisible by 4
    int4*       gb = (int4*)(buf + (size_t)node0 * CAP);
    const int4* lb = (const int4*)lbuf;
    for (int i = tid; i < vecs; i += 256) gb[i] = lb[i];
    for (int t = tid; t < nn; t += 256) {
        int c = lcnt[t];
        cnt[node0 + t]  = c;
        dinv[node0 + t] = rsqrtf((float)(c + 1));       // +1 self loop
    }
}

// ---------------- GEMM1: h[r][c] = dinv[r] * sum_k x[r][k] W[k][c] -----------
// Block 512 = 8 waves, 128 rows/block. W (64 KB) in LDS unpadded; reads use the
// split-column trick (cols {tx*4, 64+tx*4}) -> 2-way bank aliasing only (free).
__global__ __launch_bounds__(512) void gemm1_kernel(const float* __restrict__ x,
                                                    const float* __restrict__ W,
                                                    const float* __restrict__ dinv,
                                                    float* __restrict__ h, int n) {
    __shared__ float Wl[DFEAT * DFEAT];
    int tid = threadIdx.x;
#pragma unroll
    for (int it = 0; it < 8; ++it) {
        int idx = tid * 4 + it * 2048;
        *(float4*)(&Wl[idx]) = *(const float4*)(W + idx);
    }
    __syncthreads();

    int ty = tid >> 4;
    int tx = tid & 15;
    int row0 = blockIdx.x * 128 + ty * 4;
    int c0a = tx * 4, c0b = 64 + tx * 4;

    int rr[4];
#pragma unroll
    for (int i = 0; i < 4; i++) { int r = row0 + i; rr[i] = (r < n) ? r : (n - 1); }

    float acc[4][8];
#pragma unroll
    for (int i = 0; i < 4; i++)
#pragma unroll
        for (int j = 0; j < 8; j++) acc[i][j] = 0.f;

    for (int k = 0; k < DFEAT; k += 4) {
        float4 a[4];
#pragma unroll
        for (int i = 0; i < 4; i++)
            a[i] = *(const float4*)(x + (size_t)rr[i] * DFEAT + k);
#pragma unroll
        for (int kk = 0; kk < 4; kk++) {
            float4 w0 = *(const float4*)(&Wl[(k + kk) * DFEAT + c0a]);
            float4 w1 = *(const float4*)(&Wl[(k + kk) * DFEAT + c0b]);
#pragma unroll
            for (int i = 0; i < 4; i++) {
                float av = (kk == 0) ? a[i].x : (kk == 1) ? a[i].y : (kk == 2) ? a[i].z : a[i].w;
                acc[i][0] = fmaf(av, w0.x, acc[i][0]);
                acc[i][1] = fmaf(av, w0.y, acc[i][1]);
                acc[i][2] = fmaf(av, w0.z, acc[i][2]);
                acc[i][3] = fmaf(av, w0.w, acc[i][3]);
                acc[i][4] = fmaf(av, w1.x, acc[i][4]);
                acc[i][5] = fmaf(av, w1.y, acc[i][5]);
                acc[i][6] = fmaf(av, w1.z, acc[i][6]);
                acc[i][7] = fmaf(av, w1.w, acc[i][7]);
            }
        }
    }
#pragma unroll
    for (int i = 0; i < 4; i++) {
        int r = row0 + i;
        if (r < n) {
            float s = dinv[r];
            float4 o0 = make_float4(acc[i][0] * s, acc[i][1] * s, acc[i][2] * s, acc[i][3] * s);
            float4 o1 = make_float4(acc[i][4] * s, acc[i][5] * s, acc[i][6] * s, acc[i][7] * s);
            *(float4*)(h + (size_t)r * DFEAT + c0a) = o0;
            *(float4*)(h + (size_t)r * DFEAT + c0b) = o1;
        }
    }
}

// ---------------- propagate: agg[i] = dinv[i]*(h'[i] + sum_src h'[src]) ------
__global__ __launch_bounds__(256) void propagate_kernel(const float* __restrict__ h,
                                                        const int* __restrict__ buf,
                                                        const int* __restrict__ cnt,
                                                        const float* __restrict__ dinv,
                                                        float* __restrict__ agg, int n) {
    int wave = (blockIdx.x * 256 + threadIdx.x) >> 6;
    int lane = threadIdx.x & 63;
    if (wave >= n) return;

    int c = cnt[wave];
    if (c > CAP) c = CAP;
    float di = dinv[wave];

    int mysrc = 0;
    if (lane < c) mysrc = buf[wave * CAP + lane];

    const float2* h2 = (const float2*)h;
    float2 acc = h2[(size_t)wave * 64 + lane];   // self term

    int k = 0;
    for (; k + 7 < c; k += 8) {
        int s[8];
#pragma unroll
        for (int j = 0; j < 8; j++) s[j] = __shfl(mysrc, k + j);
        float2 v[8];
#pragma unroll
        for (int j = 0; j < 8; j++) v[j] = h2[(size_t)s[j] * 64 + lane];
        float sx = ((v[0].x + v[1].x) + (v[2].x + v[3].x)) +
                   ((v[4].x + v[5].x) + (v[6].x + v[7].x));
        float sy = ((v[0].y + v[1].y) + (v[2].y + v[3].y)) +
                   ((v[4].y + v[5].y) + (v[6].y + v[7].y));
        acc.x += sx;
        acc.y += sy;
    }
    for (; k < c; k++) {
        int sidx = __shfl(mysrc, k);
        float2 v = h2[(size_t)sidx * 64 + lane];
        acc.x += v.x;
        acc.y += v.y;
    }
    acc.x *= di;
    acc.y *= di;
    ((float2*)agg)[(size_t)wave * 64 + lane] = acc;
}

// ---------------- spill fix-up: agg[dst] += h'[src] * dinv[dst] --------------
__global__ __launch_bounds__(256) void spill_kernel(const float* __restrict__ h,
                                                    const int2* __restrict__ spill,
                                                    const int* __restrict__ spillcnt,
                                                    const float* __restrict__ dinv,
                                                    float* __restrict__ agg) {
    int w = (blockIdx.x * 256 + threadIdx.x) >> 6;
    int lane = threadIdx.x & 63;
    int sc = *spillcnt;
    if (sc > SPILLMAX) sc = SPILLMAX;
    if (w >= sc) return;
    int2 e = spill[w];
    float di = dinv[e.x];
    const float2* h2 = (const float2*)h;
    float2 v = h2[(size_t)e.y * 64 + lane];
    atomicAdd(&agg[(size_t)e.x * DFEAT + 2 * lane],     v.x * di);
    atomicAdd(&agg[(size_t)e.x * DFEAT + 2 * lane + 1], v.y * di);
}

// ---------------- GEMM2: out = relu( relu(agg+b) @ Wln^T + x ) ---------------
__device__ __forceinline__ int swz(int k, int c) { return c ^ (((k >> 2) & 7) << 2); }

__global__ __launch_bounds__(512) void gemm2_kernel(const float* __restrict__ agg,
                                                    const float* __restrict__ Wln,
                                                    const float* __restrict__ bias,
                                                    const float* __restrict__ x,
                                                    float* __restrict__ out, int n) {
    __shared__ float Wl[DFEAT * DFEAT];
    int tid = threadIdx.x;
#pragma unroll
    for (int it = 0; it < 8; ++it) {
        int idx = tid * 4 + it * 2048;
        float4 v = *(const float4*)(Wln + idx);
        int o  = idx >> 7;
        int ii = idx & 127;
        Wl[(ii + 0) * DFEAT + swz(ii + 0, o)] = v.x;
        Wl[(ii + 1) * DFEAT + swz(ii + 1, o)] = v.y;
        Wl[(ii + 2) * DFEAT + swz(ii + 2, o)] = v.z;
        Wl[(ii + 3) * DFEAT + swz(ii + 3, o)] = v.w;
    }
    __syncthreads();

    int ty = tid >> 4;
    int tx = tid & 15;
    int row0 = blockIdx.x * 128 + ty * 4;
    int c0a = tx * 4, c0b = 64 + tx * 4;

    int rr[4];
#pragma unroll
    for (int i = 0; i < 4; i++) { int r = row0 + i; rr[i] = (r < n) ? r : (n - 1); }

    float acc[4][8];
#pragma unroll
    for (int i = 0; i < 4; i++)
#pragma unroll
        for (int j = 0; j < 8; j++) acc[i][j] = 0.f;

    for (int k = 0; k < DFEAT; k += 4) {
        float4 bv = *(const float4*)(bias + k);
        float4 a[4];
#pragma unroll
        for (int i = 0; i < 4; i++) {
            float4 v = *(const float4*)(agg + (size_t)rr[i] * DFEAT + k);
            v.x = fmaxf(v.x + bv.x, 0.f);
            v.y = fmaxf(v.y + bv.y, 0.f);
            v.z = fmaxf(v.z + bv.z, 0.f);
            v.w = fmaxf(v.w + bv.w, 0.f);
            a[i] = v;
        }
#pragma unroll
        for (int kk = 0; kk < 4; kk++) {
            int krow = k + kk;
            float4 w0 = *(const float4*)(&Wl[krow * DFEAT + swz(krow, c0a)]);
            float4 w1 = *(const float4*)(&Wl[krow * DFEAT + swz(krow, c0b)]);
#pragma unroll
            for (int i = 0; i < 4; i++) {
                float av = (kk == 0) ? a[i].x : (kk == 1) ? a[i].y : (kk == 2) ? a[i].z : a[i].w;
                acc[i][0] = fmaf(av, w0.x, acc[i][0]);
                acc[i][1] = fmaf(av, w0.y, acc[i][1]);
                acc[i][2] = fmaf(av, w0.z, acc[i][2]);
                acc[i][3] = fmaf(av, w0.w, acc[i][3]);
                acc[i][4] = fmaf(av, w1.x, acc[i][4]);
                acc[i][5] = fmaf(av, w1.y, acc[i][5]);
                acc[i][6] = fmaf(av, w1.z, acc[i][6]);
                acc[i][7] = fmaf(av, w1.w, acc[i][7]);
            }
        }
    }
#pragma unroll
    for (int i = 0; i < 4; i++) {
        int r = row0 + i;
        if (r < n) {
            float4 x0 = *(const float4*)(x + (size_t)r * DFEAT + c0a);
            float4 x1 = *(const float4*)(x + (size_t)r * DFEAT + c0b);
            float4 o0 = make_float4(fmaxf(acc[i][0] + x0.x, 0.f), fmaxf(acc[i][1] + x0.y, 0.f),
                                    fmaxf(acc[i][2] + x0.z, 0.f), fmaxf(acc[i][3] + x0.w, 0.f));
            float4 o1 = make_float4(fmaxf(acc[i][4] + x1.x, 0.f), fmaxf(acc[i][5] + x1.y, 0.f),
                                    fmaxf(acc[i][6] + x1.z, 0.f), fmaxf(acc[i][7] + x1.w, 0.f));
            *(float4*)(out + (size_t)r * DFEAT + c0a) = o0;
            *(float4*)(out + (size_t)r * DFEAT + c0b) = o1;
        }
    }
}

extern "C" void kernel_launch(void* const* d_in, const int* in_sizes, int n_in,
                              void* d_out, int out_size, void* d_ws, size_t ws_size,
                              hipStream_t stream) {
    const float* x    = (const float*)d_in[0];
    const int*   ei   = (const int*)d_in[1];
    const float* Wg   = (const float*)d_in[2];
    const float* bg   = (const float*)d_in[3];
    const float* Wln  = (const float*)d_in[4];
    float*       out  = (float*)d_out;

    int n = in_sizes[0] / DFEAT;   // 100000
    int E = in_sizes[1] / 2;       // 1600000
    int K = (n + PNODES - 1) >> PSH;  // 196 partitions

    // workspace (256B-aligned): gcur | spc | cnt | dinv | spill | rec | buf | h  (~73 MB)
    size_t off = 0;
    auto take = [&](size_t bytes) {
        void* p = (char*)d_ws + off;
        off += (bytes + 255) & ~(size_t)255;
        return p;
    };
    int*      gcur  = (int*)take((size_t)PMAX * 4);
    int*      spc   = (int*)take(256);
    int*      cnt   = (int*)take((size_t)n * 4);
    float*    dinv  = (float*)take((size_t)n * 4);
    int2*     spill = (int2*)take((size_t)SPILLMAX * 8);
    unsigned* rec   = (unsigned*)take((size_t)K * REGCAP * 4);
    int*      buf   = (int*)take((size_t)n * CAP * 4);
    float*    h     = (float*)take((size_t)n * DFEAT * 4);

    hipMemsetAsync(gcur, 0, (size_t)PMAX * 4, stream);
    hipMemsetAsync(spc, 0, 4, stream);
    partA_kernel<<<(E + CHUNK - 1) / CHUNK, 256, 0, stream>>>(ei, rec, gcur, spill, spc, E);
    partB_kernel<<<K, 256, 0, stream>>>(rec, gcur, buf, cnt, dinv, spill, spc, n);
    gemm1_kernel<<<(n + 127) / 128, 512, 0, stream>>>(x, Wg, dinv, h, n);
    propagate_kernel<<<(n + 3) / 4, 256, 0, stream>>>(h, buf, cnt, dinv, out, n);
    spill_kernel<<<SPILLMAX / 4, 256, 0, stream>>>(h, spill, spc, dinv, out);
    gemm2_kernel<<<(n + 127) / 128, 512, 0, stream>>>(out, Wln, bg, x, out, n);
}

// Round 10
// 326.022 us; speedup vs baseline: 1.4394x; 1.1781x over previous
//
#include <hip/hip_runtime.h>

#define DFEAT 128
#define CAP   32        // per-node bucket entries; overflow -> exact spill list
#define PSH   9         // partition shift: 512 nodes/partition
#define PNODES (1 << PSH)
#define PMAX  1024      // supports n up to 512K nodes
#define REGCAP 10240    // records/partition region (mean E*512/n=8163, >20 sigma)
#define SPILLMAX 4096
#define CHUNK 4096      // edges per block in pass A

// pack two f32 -> two bf16 (round-to-nearest-even) in one uint
__device__ __forceinline__ unsigned pack_bf16_2(float a, float b) {
    unsigned ua = __float_as_uint(a);
    unsigned ub = __float_as_uint(b);
    ua = (ua + 0x7FFFu + ((ua >> 16) & 1u)) >> 16;
    ub = (ub + 0x7FFFu + ((ub >> 16) & 1u)) >> 16;
    return ua | (ub << 16);
}

// ---------------- pass A: partition edges by dst>>9 into per-partition regions
__global__ __launch_bounds__(256) void partA_kernel(const int* __restrict__ ei,
                                                    unsigned* __restrict__ rec,
                                                    int* __restrict__ gcur,
                                                    int2* __restrict__ spill,
                                                    int* __restrict__ spillcnt,
                                                    int E) {
    __shared__ int lhist[PMAX];
    int tid  = threadIdx.x;
    int base = blockIdx.x * CHUNK;
    int end  = min(base + CHUNK, E);
    for (int i = tid; i < PMAX; i += 256) lhist[i] = 0;
    __syncthreads();
    for (int e = base + tid; e < end; e += 256) {
        int dst = ei[E + e];
        atomicAdd(&lhist[dst >> PSH], 1);
    }
    __syncthreads();
    for (int p = tid; p < PMAX; p += 256) {
        int c = lhist[p];
        if (c > 0) lhist[p] = atomicAdd(&gcur[p], c);   // count -> global base
    }
    __syncthreads();
    for (int e = base + tid; e < end; e += 256) {
        int src = ei[e];
        int dst = ei[E + e];
        int p   = dst >> PSH;
        int off = atomicAdd(&lhist[p], 1);              // absolute offset in region
        if (off < REGCAP) {
            rec[(size_t)p * REGCAP + off] =
                ((unsigned)(dst & (PNODES - 1)) << 23) | (unsigned)src;
        } else {
            int sp = atomicAdd(spillcnt, 1);
            if (sp < SPILLMAX) spill[sp] = make_int2(dst, src);
        }
    }
}

// ---------------- pass B: per-partition bucket build entirely in LDS ---------
__global__ __launch_bounds__(256) void partB_kernel(const unsigned* __restrict__ rec,
                                                    const int* __restrict__ gcur,
                                                    int* __restrict__ buf,
                                                    int* __restrict__ cnt,
                                                    float* __restrict__ dinv,
                                                    int2* __restrict__ spill,
                                                    int* __restrict__ spillcnt,
                                                    int n) {
    __shared__ int lcnt[PNODES];
    __shared__ int lbuf[PNODES * CAP];                  // 64 KB
    int tid   = threadIdx.x;
    int p     = blockIdx.x;
    int node0 = p << PSH;
    for (int i = tid; i < PNODES; i += 256) lcnt[i] = 0;
    __syncthreads();
    int total = gcur[p];
    if (total > REGCAP) total = REGCAP;
    const unsigned* r = rec + (size_t)p * REGCAP;
    for (int i = tid; i < total; i += 256) {
        unsigned v = r[i];
        int ldst = (int)(v >> 23);
        int src  = (int)(v & 0x7FFFFFu);
        int pos  = atomicAdd(&lcnt[ldst], 1);           // true in-degree counter
        if (pos < CAP) lbuf[(ldst << 5) + pos] = src;
        else {
            int sp = atomicAdd(spillcnt, 1);
            if (sp < SPILLMAX) spill[sp] = make_int2(node0 + ldst, src);
        }
    }
    __syncthreads();
    int nn = min(PNODES, n - node0);
    if (nn <= 0) return;
    int vecs = (nn * CAP) >> 2;
    int4*       gb = (int4*)(buf + (size_t)node0 * CAP);
    const int4* lb = (const int4*)lbuf;
    for (int i = tid; i < vecs; i += 256) gb[i] = lb[i];
    for (int t = tid; t < nn; t += 256) {
        int c = lcnt[t];
        cnt[node0 + t]  = c;
        dinv[node0 + t] = rsqrtf((float)(c + 1));       // +1 self loop
    }
}

// ---------------- GEMM1: h[r][c] = bf16( dinv[r] * sum_k x[r][k] W[k][c] ) ---
// h stored as packed bf16 pairs (uint): row = 64 uints = 256 B. Halves the
// propagate gather working set (25.6 MB) and demand bytes.
__global__ __launch_bounds__(512) void gemm1_kernel(const float* __restrict__ x,
                                                    const float* __restrict__ W,
                                                    const float* __restrict__ dinv,
                                                    unsigned* __restrict__ h, int n) {
    __shared__ float Wl[DFEAT * DFEAT];
    int tid = threadIdx.x;
#pragma unroll
    for (int it = 0; it < 8; ++it) {
        int idx = tid * 4 + it * 2048;
        *(float4*)(&Wl[idx]) = *(const float4*)(W + idx);
    }
    __syncthreads();

    int ty = tid >> 4;
    int tx = tid & 15;
    int row0 = blockIdx.x * 128 + ty * 4;
    int c0a = tx * 4, c0b = 64 + tx * 4;

    int rr[4];
#pragma unroll
    for (int i = 0; i < 4; i++) { int r = row0 + i; rr[i] = (r < n) ? r : (n - 1); }

    float acc[4][8];
#pragma unroll
    for (int i = 0; i < 4; i++)
#pragma unroll
        for (int j = 0; j < 8; j++) acc[i][j] = 0.f;

    for (int k = 0; k < DFEAT; k += 4) {
        float4 a[4];
#pragma unroll
        for (int i = 0; i < 4; i++)
            a[i] = *(const float4*)(x + (size_t)rr[i] * DFEAT + k);
#pragma unroll
        for (int kk = 0; kk < 4; kk++) {
            float4 w0 = *(const float4*)(&Wl[(k + kk) * DFEAT + c0a]);
            float4 w1 = *(const float4*)(&Wl[(k + kk) * DFEAT + c0b]);
#pragma unroll
            for (int i = 0; i < 4; i++) {
                float av = (kk == 0) ? a[i].x : (kk == 1) ? a[i].y : (kk == 2) ? a[i].z : a[i].w;
                acc[i][0] = fmaf(av, w0.x, acc[i][0]);
                acc[i][1] = fmaf(av, w0.y, acc[i][1]);
                acc[i][2] = fmaf(av, w0.z, acc[i][2]);
                acc[i][3] = fmaf(av, w0.w, acc[i][3]);
                acc[i][4] = fmaf(av, w1.x, acc[i][4]);
                acc[i][5] = fmaf(av, w1.y, acc[i][5]);
                acc[i][6] = fmaf(av, w1.z, acc[i][6]);
                acc[i][7] = fmaf(av, w1.w, acc[i][7]);
            }
        }
    }
#pragma unroll
    for (int i = 0; i < 4; i++) {
        int r = row0 + i;
        if (r < n) {
            float s = dinv[r];
            uint2 o0 = make_uint2(pack_bf16_2(acc[i][0] * s, acc[i][1] * s),
                                  pack_bf16_2(acc[i][2] * s, acc[i][3] * s));
            uint2 o1 = make_uint2(pack_bf16_2(acc[i][4] * s, acc[i][5] * s),
                                  pack_bf16_2(acc[i][6] * s, acc[i][7] * s));
            *(uint2*)(h + (size_t)r * 64 + tx * 2)      = o0;   // cols c0a..c0a+3
            *(uint2*)(h + (size_t)r * 64 + 32 + tx * 2) = o1;   // cols c0b..c0b+3
        }
    }
}

// ---------------- propagate: agg[i] = dinv[i]*(h'[i] + sum_src h'[src]) ------
// One wave per node; lane owns one packed uint (2 bf16 feats) of the 256 B row.
// 8 independent 4B loads in flight per lane; unpack is shift/mask (exact).
__global__ __launch_bounds__(256) void propagate_kernel(const unsigned* __restrict__ h,
                                                        const int* __restrict__ buf,
                                                        const int* __restrict__ cnt,
                                                        const float* __restrict__ dinv,
                                                        float* __restrict__ agg, int n) {
    int wave = (blockIdx.x * 256 + threadIdx.x) >> 6;
    int lane = threadIdx.x & 63;
    if (wave >= n) return;

    int c = cnt[wave];
    if (c > CAP) c = CAP;
    float di = dinv[wave];

    int mysrc = 0;
    if (lane < c) mysrc = buf[wave * CAP + lane];

    unsigned sv = h[(size_t)wave * 64 + lane];          // self term
    float ax = __uint_as_float(sv << 16);
    float ay = __uint_as_float(sv & 0xFFFF0000u);

    int k = 0;
    for (; k + 7 < c; k += 8) {
        int s[8];
#pragma unroll
        for (int j = 0; j < 8; j++) s[j] = __shfl(mysrc, k + j);
        unsigned v[8];
#pragma unroll
        for (int j = 0; j < 8; j++) v[j] = h[(size_t)s[j] * 64 + lane];
        float sx = 0.f, sy = 0.f;
#pragma unroll
        for (int j = 0; j < 8; j++) {
            sx += __uint_as_float(v[j] << 16);
            sy += __uint_as_float(v[j] & 0xFFFF0000u);
        }
        ax += sx;
        ay += sy;
    }
    for (; k < c; k++) {
        int sidx = __shfl(mysrc, k);
        unsigned v = h[(size_t)sidx * 64 + lane];
        ax += __uint_as_float(v << 16);
        ay += __uint_as_float(v & 0xFFFF0000u);
    }
    float2 acc = make_float2(ax * di, ay * di);
    ((float2*)agg)[(size_t)wave * 64 + lane] = acc;
}

// ---------------- spill fix-up: agg[dst] += h'[src] * dinv[dst] --------------
__global__ __launch_bounds__(256) void spill_kernel(const unsigned* __restrict__ h,
                                                    const int2* __restrict__ spill,
                                                    const int* __restrict__ spillcnt,
                                                    const float* __restrict__ dinv,
                                                    float* __restrict__ agg) {
    int w = (blockIdx.x * 256 + threadIdx.x) >> 6;
    int lane = threadIdx.x & 63;
    int sc = *spillcnt;
    if (sc > SPILLMAX) sc = SPILLMAX;
    if (w >= sc) return;
    int2 e = spill[w];
    float di = dinv[e.x];
    unsigned v = h[(size_t)e.y * 64 + lane];
    atomicAdd(&agg[(size_t)e.x * DFEAT + 2 * lane],     __uint_as_float(v << 16) * di);
    atomicAdd(&agg[(size_t)e.x * DFEAT + 2 * lane + 1], __uint_as_float(v & 0xFFFF0000u) * di);
}

// ---------------- GEMM2: out = relu( relu(agg+b) @ Wln^T + x ) ---------------
__device__ __forceinline__ int swz(int k, int c) { return c ^ (((k >> 2) & 7) << 2); }

__global__ __launch_bounds__(512) void gemm2_kernel(const float* __restrict__ agg,
                                                    const float* __restrict__ Wln,
                                                    const float* __restrict__ bias,
                                                    const float* __restrict__ x,
                                                    float* __restrict__ out, int n) {
    __shared__ float Wl[DFEAT * DFEAT];
    int tid = threadIdx.x;
#pragma unroll
    for (int it = 0; it < 8; ++it) {
        int idx = tid * 4 + it * 2048;
        float4 v = *(const float4*)(Wln + idx);
        int o  = idx >> 7;
        int ii = idx & 127;
        Wl[(ii + 0) * DFEAT + swz(ii + 0, o)] = v.x;
        Wl[(ii + 1) * DFEAT + swz(ii + 1, o)] = v.y;
        Wl[(ii + 2) * DFEAT + swz(ii + 2, o)] = v.z;
        Wl[(ii + 3) * DFEAT + swz(ii + 3, o)] = v.w;
    }
    __syncthreads();

    int ty = tid >> 4;
    int tx = tid & 15;
    int row0 = blockIdx.x * 128 + ty * 4;
    int c0a = tx * 4, c0b = 64 + tx * 4;

    int rr[4];
#pragma unroll
    for (int i = 0; i < 4; i++) { int r = row0 + i; rr[i] = (r < n) ? r : (n - 1); }

    float acc[4][8];
#pragma unroll
    for (int i = 0; i < 4; i++)
#pragma unroll
        for (int j = 0; j < 8; j++) acc[i][j] = 0.f;

    for (int k = 0; k < DFEAT; k += 4) {
        float4 bv = *(const float4*)(bias + k);
        float4 a[4];
#pragma unroll
        for (int i = 0; i < 4; i++) {
            float4 v = *(const float4*)(agg + (size_t)rr[i] * DFEAT + k);
            v.x = fmaxf(v.x + bv.x, 0.f);
            v.y = fmaxf(v.y + bv.y, 0.f);
            v.z = fmaxf(v.z + bv.z, 0.f);
            v.w = fmaxf(v.w + bv.w, 0.f);
            a[i] = v;
        }
#pragma unroll
        for (int kk = 0; kk < 4; kk++) {
            int krow = k + kk;
            float4 w0 = *(const float4*)(&Wl[krow * DFEAT + swz(krow, c0a)]);
            float4 w1 = *(const float4*)(&Wl[krow * DFEAT + swz(krow, c0b)]);
#pragma unroll
            for (int i = 0; i < 4; i++) {
                float av = (kk == 0) ? a[i].x : (kk == 1) ? a[i].y : (kk == 2) ? a[i].z : a[i].w;
                acc[i][0] = fmaf(av, w0.x, acc[i][0]);
                acc[i][1] = fmaf(av, w0.y, acc[i][1]);
                acc[i][2] = fmaf(av, w0.z, acc[i][2]);
                acc[i][3] = fmaf(av, w0.w, acc[i][3]);
                acc[i][4] = fmaf(av, w1.x, acc[i][4]);
                acc[i][5] = fmaf(av, w1.y, acc[i][5]);
                acc[i][6] = fmaf(av, w1.z, acc[i][6]);
                acc[i][7] = fmaf(av, w1.w, acc[i][7]);
            }
        }
    }
#pragma unroll
    for (int i = 0; i < 4; i++) {
        int r = row0 + i;
        if (r < n) {
            float4 x0 = *(const float4*)(x + (size_t)r * DFEAT + c0a);
            float4 x1 = *(const float4*)(x + (size_t)r * DFEAT + c0b);
            float4 o0 = make_float4(fmaxf(acc[i][0] + x0.x, 0.f), fmaxf(acc[i][1] + x0.y, 0.f),
                                    fmaxf(acc[i][2] + x0.z, 0.f), fmaxf(acc[i][3] + x0.w, 0.f));
            float4 o1 = make_float4(fmaxf(acc[i][4] + x1.x, 0.f), fmaxf(acc[i][5] + x1.y, 0.f),
                                    fmaxf(acc[i][6] + x1.z, 0.f), fmaxf(acc[i][7] + x1.w, 0.f));
            *(float4*)(out + (size_t)r * DFEAT + c0a) = o0;
            *(float4*)(out + (size_t)r * DFEAT + c0b) = o1;
        }
    }
}

extern "C" void kernel_launch(void* const* d_in, const int* in_sizes, int n_in,
                              void* d_out, int out_size, void* d_ws, size_t ws_size,
                              hipStream_t stream) {
    const float* x    = (const float*)d_in[0];
    const int*   ei   = (const int*)d_in[1];
    const float* Wg   = (const float*)d_in[2];
    const float* bg   = (const float*)d_in[3];
    const float* Wln  = (const float*)d_in[4];
    float*       out  = (float*)d_out;

    int n = in_sizes[0] / DFEAT;   // 100000
    int E = in_sizes[1] / 2;       // 1600000
    int K = (n + PNODES - 1) >> PSH;  // 196 partitions

    // workspace (256B-aligned): gcur | spc | cnt | dinv | spill | rec | buf | h
    size_t off = 0;
    auto take = [&](size_t bytes) {
        void* p = (char*)d_ws + off;
        off += (bytes + 255) & ~(size_t)255;
        return p;
    };
    int*      gcur  = (int*)take((size_t)PMAX * 4);
    int*      spc   = (int*)take(256);
    int*      cnt   = (int*)take((size_t)n * 4);
    float*    dinv  = (float*)take((size_t)n * 4);
    int2*     spill = (int2*)take((size_t)SPILLMAX * 8);
    unsigned* rec   = (unsigned*)take((size_t)K * REGCAP * 4);
    int*      buf   = (int*)take((size_t)n * CAP * 4);
    unsigned* h     = (unsigned*)take((size_t)n * 64 * 4);   // bf16x2 packed

    hipMemsetAsync(gcur, 0, (size_t)PMAX * 4, stream);
    hipMemsetAsync(spc, 0, 4, stream);
    partA_kernel<<<(E + CHUNK - 1) / CHUNK, 256, 0, stream>>>(ei, rec, gcur, spill, spc, E);
    partB_kernel<<<K, 256, 0, stream>>>(rec, gcur, buf, cnt, dinv, spill, spc, n);
    gemm1_kernel<<<(n + 127) / 128, 512, 0, stream>>>(x, Wg, dinv, h, n);
    propagate_kernel<<<(n + 3) / 4, 256, 0, stream>>>(h, buf, cnt, dinv, out, n);
    spill_kernel<<<SPILLMAX / 4, 256, 0, stream>>>(h, spill, spc, dinv, out);
    gemm2_kernel<<<(n + 127) / 128, 512, 0, stream>>>(out, Wln, bg, x, out, n);
}

// Round 12
// 281.711 us; speedup vs baseline: 1.6658x; 1.1573x over previous
//
#include <hip/hip_runtime.h>

#define DFEAT 128
#define CAP   32        // per-node bucket entries; overflow -> exact spill list
#define PSH   9         // partition shift: 512 nodes/partition
#define PNODES (1 << PSH)
#define PMAX  1024
#define REGCAP 10240    // records/partition region (mean 8163, >20 sigma)
#define SPILLMAX 4096
#define CHUNK 4096      // edges per block in pass A
#define GROWS 192       // rows per GEMM block: 4 waves x 3 strips x 16

typedef __attribute__((ext_vector_type(8))) short bf16x8;
typedef __attribute__((ext_vector_type(4))) float f32x4;

__device__ __forceinline__ unsigned bf16_rtn(float x) {   // f32 -> bf16 bits (RTN-even)
    unsigned u = __float_as_uint(x);
    return (u + 0x7FFFu + ((u >> 16) & 1u)) >> 16;
}
__device__ __forceinline__ float bf16f(unsigned b) { return __uint_as_float(b << 16); }
__device__ __forceinline__ unsigned pack_bf16_2(float a, float b) {
    return bf16_rtn(a) | (bf16_rtn(b) << 16);
}

// ---------------- pass A: partition edges by dst>>9 into per-partition regions
__global__ __launch_bounds__(256) void partA_kernel(const int* __restrict__ ei,
                                                    unsigned* __restrict__ rec,
                                                    int* __restrict__ gcur,
                                                    int2* __restrict__ spill,
                                                    int* __restrict__ spillcnt,
                                                    int E) {
    __shared__ int lhist[PMAX];
    int tid  = threadIdx.x;
    int base = blockIdx.x * CHUNK;
    int end  = min(base + CHUNK, E);
    for (int i = tid; i < PMAX; i += 256) lhist[i] = 0;
    __syncthreads();
    for (int e = base + tid; e < end; e += 256) {
        int dst = ei[E + e];
        atomicAdd(&lhist[dst >> PSH], 1);
    }
    __syncthreads();
    for (int p = tid; p < PMAX; p += 256) {
        int c = lhist[p];
        if (c > 0) lhist[p] = atomicAdd(&gcur[p], c);
    }
    __syncthreads();
    for (int e = base + tid; e < end; e += 256) {
        int src = ei[e];
        int dst = ei[E + e];
        int p   = dst >> PSH;
        int off = atomicAdd(&lhist[p], 1);
        if (off < REGCAP) {
            rec[(size_t)p * REGCAP + off] =
                ((unsigned)(dst & (PNODES - 1)) << 23) | (unsigned)src;
        } else {
            int sp = atomicAdd(spillcnt, 1);
            if (sp < SPILLMAX) spill[sp] = make_int2(dst, src);
        }
    }
}

// ---------------- pass B: per-partition bucket build entirely in LDS ---------
__global__ __launch_bounds__(256) void partB_kernel(const unsigned* __restrict__ rec,
                                                    const int* __restrict__ gcur,
                                                    int* __restrict__ buf,
                                                    int* __restrict__ cnt,
                                                    float* __restrict__ dinv,
                                                    int2* __restrict__ spill,
                                                    int* __restrict__ spillcnt,
                                                    int n) {
    __shared__ int lcnt[PNODES];
    __shared__ int lbuf[PNODES * CAP];
    int tid   = threadIdx.x;
    int p     = blockIdx.x;
    int node0 = p << PSH;
    for (int i = tid; i < PNODES; i += 256) lcnt[i] = 0;
    __syncthreads();
    int total = gcur[p];
    if (total > REGCAP) total = REGCAP;
    const unsigned* r = rec + (size_t)p * REGCAP;
    for (int i = tid; i < total; i += 256) {
        unsigned v = r[i];
        int ldst = (int)(v >> 23);
        int src  = (int)(v & 0x7FFFFFu);
        int pos  = atomicAdd(&lcnt[ldst], 1);
        if (pos < CAP) lbuf[(ldst << 5) + pos] = src;
        else {
            int sp = atomicAdd(spillcnt, 1);
            if (sp < SPILLMAX) spill[sp] = make_int2(node0 + ldst, src);
        }
    }
    __syncthreads();
    int nn = min(PNODES, n - node0);
    if (nn <= 0) return;
    int vecs = (nn * CAP) >> 2;
    int4*       gb = (int4*)(buf + (size_t)node0 * CAP);
    const int4* lb = (const int4*)lbuf;
    for (int i = tid; i < vecs; i += 256) gb[i] = lb[i];
    for (int t = tid; t < nn; t += 256) {
        int c = lcnt[t];
        cnt[node0 + t]  = c;
        dinv[node0 + t] = rsqrtf((float)(c + 1));
    }
}

// ---------------- GEMM1 (MFMA bf16x3): h = bf16( dinv * (x @ W) ) ------------
// W staged TRANSPOSED (Wt[c][k], k-consecutive per lane) hi/lo bf16 in LDS,
// XOR-16B swizzle -> uniform bank coverage for ds_read_b128. A (x) built
// in-register with hi/lo split. 3 MFMAs per tile: AhBh + AlBh + AhBl.
__global__ __launch_bounds__(256) void gemm1_kernel(const float* __restrict__ x,
                                                    const float* __restrict__ W,
                                                    const float* __restrict__ dinv,
                                                    unsigned* __restrict__ h, int n) {
    __shared__ unsigned short Wh[DFEAT * DFEAT];   // 32 KB
    __shared__ unsigned short Wl[DFEAT * DFEAT];   // 32 KB
    int tid = threadIdx.x;
    {   // stage W^T: thread owns column c, 64 k's; coalesced dword reads
        int c = tid & 127, kh = tid >> 7;
        for (int kc = 0; kc < 64; kc += 8) {
            int k0 = kh * 64 + kc;
            float w8[8];
#pragma unroll
            for (int j = 0; j < 8; j++) w8[j] = W[(size_t)(k0 + j) * DFEAT + c];
            bf16x8 hv, lv;
#pragma unroll
            for (int j = 0; j < 8; j++) {
                unsigned hb = bf16_rtn(w8[j]);
                hv[j] = (short)hb;
                lv[j] = (short)bf16_rtn(w8[j] - bf16f(hb));
            }
            int byte = (c << 8) + ((k0 * 2) ^ ((c & 7) << 4));
            *(bf16x8*)((char*)Wh + byte) = hv;
            *(bf16x8*)((char*)Wl + byte) = lv;
        }
    }
    __syncthreads();

    int w    = tid >> 6;            // wave 0..3
    int l    = tid & 63;
    int row0 = blockIdx.x * GROWS + w * 48;
    int lr   = l & 15;              // row-in-strip (A) / col-in-tile (B,D)
    int lq   = l >> 4;              // k-octet quadrant

    f32x4 acc[3][8];
#pragma unroll
    for (int s = 0; s < 3; s++)
#pragma unroll
        for (int ct = 0; ct < 8; ct++) acc[s][ct] = (f32x4){0.f, 0.f, 0.f, 0.f};

    for (int kt = 0; kt < 4; kt++) {
        int k0 = kt * 32 + lq * 8;
        bf16x8 ah[3], al[3];
#pragma unroll
        for (int s = 0; s < 3; s++) {
            int rw = row0 + s * 16 + lr;
            int rc = (rw < n) ? rw : (n - 1);
            const float* xp = x + (size_t)rc * DFEAT + k0;
            float v[8];
            *(float4*)(v)     = *(const float4*)(xp);
            *(float4*)(v + 4) = *(const float4*)(xp + 4);
#pragma unroll
            for (int j = 0; j < 8; j++) {
                unsigned hb = bf16_rtn(v[j]);
                ah[s][j] = (short)hb;
                al[s][j] = (short)bf16_rtn(v[j] - bf16f(hb));
            }
        }
#pragma unroll
        for (int ct = 0; ct < 8; ct++) {
            int brow = ct * 16 + lr;
            int byte = (brow << 8) + ((k0 * 2) ^ ((brow & 7) << 4));
            bf16x8 bh = *(const bf16x8*)((const char*)Wh + byte);
            bf16x8 bl = *(const bf16x8*)((const char*)Wl + byte);
#pragma unroll
            for (int s = 0; s < 3; s++) {
                acc[s][ct] = __builtin_amdgcn_mfma_f32_16x16x32_bf16(ah[s], bh, acc[s][ct], 0, 0, 0);
                acc[s][ct] = __builtin_amdgcn_mfma_f32_16x16x32_bf16(al[s], bh, acc[s][ct], 0, 0, 0);
                acc[s][ct] = __builtin_amdgcn_mfma_f32_16x16x32_bf16(ah[s], bl, acc[s][ct], 0, 0, 0);
            }
        }
    }

    // epilogue: D row=(l>>4)*4+r, col=ct*16+(l&15); scale by dinv, pack bf16 pairs
#pragma unroll
    for (int s = 0; s < 3; s++) {
#pragma unroll
        for (int r = 0; r < 4; r++) {
            int rw = row0 + s * 16 + lq * 4 + r;
            int rc = (rw < n) ? rw : (n - 1);
            float di = dinv[rc];
#pragma unroll
            for (int ct = 0; ct < 8; ct++) {
                float v = acc[s][ct][r] * di;
                float o = __shfl_xor(v, 1);
                if (((l & 1) == 0) && rw < n)
                    h[(size_t)rw * 64 + ct * 8 + (lr >> 1)] = pack_bf16_2(v, o);
            }
        }
    }
}

// ---------------- propagate: agg[i] = dinv[i]*(h'[i] + sum_src h'[src]) ------
__global__ __launch_bounds__(256) void propagate_kernel(const unsigned* __restrict__ h,
                                                        const int* __restrict__ buf,
                                                        const int* __restrict__ cnt,
                                                        const float* __restrict__ dinv,
                                                        float* __restrict__ agg, int n) {
    int wave = (blockIdx.x * 256 + threadIdx.x) >> 6;
    int lane = threadIdx.x & 63;
    if (wave >= n) return;

    int c = cnt[wave];
    if (c > CAP) c = CAP;
    float di = dinv[wave];

    int mysrc = 0;
    if (lane < c) mysrc = buf[wave * CAP + lane];

    unsigned sv = h[(size_t)wave * 64 + lane];
    float ax = __uint_as_float(sv << 16);
    float ay = __uint_as_float(sv & 0xFFFF0000u);

    int k = 0;
    for (; k + 7 < c; k += 8) {
        int s[8];
#pragma unroll
        for (int j = 0; j < 8; j++) s[j] = __shfl(mysrc, k + j);
        unsigned v[8];
#pragma unroll
        for (int j = 0; j < 8; j++) v[j] = h[(size_t)s[j] * 64 + lane];
        float sx = 0.f, sy = 0.f;
#pragma unroll
        for (int j = 0; j < 8; j++) {
            sx += __uint_as_float(v[j] << 16);
            sy += __uint_as_float(v[j] & 0xFFFF0000u);
        }
        ax += sx;
        ay += sy;
    }
    for (; k < c; k++) {
        int sidx = __shfl(mysrc, k);
        unsigned v = h[(size_t)sidx * 64 + lane];
        ax += __uint_as_float(v << 16);
        ay += __uint_as_float(v & 0xFFFF0000u);
    }
    ((float2*)agg)[(size_t)wave * 64 + lane] = make_float2(ax * di, ay * di);
}

// ---------------- spill fix-up ----------------------------------------------
__global__ __launch_bounds__(256) void spill_kernel(const unsigned* __restrict__ h,
                                                    const int2* __restrict__ spill,
                                                    const int* __restrict__ spillcnt,
                                                    const float* __restrict__ dinv,
                                                    float* __restrict__ agg) {
    int w = (blockIdx.x * 256 + threadIdx.x) >> 6;
    int lane = threadIdx.x & 63;
    int sc = *spillcnt;
    if (sc > SPILLMAX) sc = SPILLMAX;
    if (w >= sc) return;
    int2 e = spill[w];
    float di = dinv[e.x];
    unsigned v = h[(size_t)e.y * 64 + lane];
    atomicAdd(&agg[(size_t)e.x * DFEAT + 2 * lane],     __uint_as_float(v << 16) * di);
    atomicAdd(&agg[(size_t)e.x * DFEAT + 2 * lane + 1], __uint_as_float(v & 0xFFFF0000u) * di);
}

// ---------------- GEMM2 (MFMA bf16x3): out = relu(relu(agg+b) @ Wln^T + x) ---
// Wln[o][k] is naturally k-consecutive for the B-operand (B[k][n]=Wln[n][k]).
// Residual + relu epilogue in exact f32.
__global__ __launch_bounds__(256) void gemm2_kernel(const float* __restrict__ agg,
                                                    const float* __restrict__ Wln,
                                                    const float* __restrict__ bias,
                                                    const float* __restrict__ x,
                                                    float* __restrict__ out, int n) {
    __shared__ unsigned short Bh[DFEAT * DFEAT];
    __shared__ unsigned short Bl[DFEAT * DFEAT];
    int tid = threadIdx.x;
    {   // stage Wln rows (contiguous float4 reads), hi/lo bf16, swizzled
        int o = tid & 127, kh = tid >> 7;
        for (int kc = 0; kc < 64; kc += 8) {
            int k0 = kh * 64 + kc;
            float w8[8];
            *(float4*)(w8)     = *(const float4*)(Wln + (size_t)o * DFEAT + k0);
            *(float4*)(w8 + 4) = *(const float4*)(Wln + (size_t)o * DFEAT + k0 + 4);
            bf16x8 hv, lv;
#pragma unroll
            for (int j = 0; j < 8; j++) {
                unsigned hb = bf16_rtn(w8[j]);
                hv[j] = (short)hb;
                lv[j] = (short)bf16_rtn(w8[j] - bf16f(hb));
            }
            int byte = (o << 8) + ((k0 * 2) ^ ((o & 7) << 4));
            *(bf16x8*)((char*)Bh + byte) = hv;
            *(bf16x8*)((char*)Bl + byte) = lv;
        }
    }
    __syncthreads();

    int w    = tid >> 6;
    int l    = tid & 63;
    int row0 = blockIdx.x * GROWS + w * 48;
    int lr   = l & 15;
    int lq   = l >> 4;

    f32x4 acc[3][8];
#pragma unroll
    for (int s = 0; s < 3; s++)
#pragma unroll
        for (int ct = 0; ct < 8; ct++) acc[s][ct] = (f32x4){0.f, 0.f, 0.f, 0.f};

    for (int kt = 0; kt < 4; kt++) {
        int k0 = kt * 32 + lq * 8;
        float bb[8];
        *(float4*)(bb)     = *(const float4*)(bias + k0);
        *(float4*)(bb + 4) = *(const float4*)(bias + k0 + 4);
        bf16x8 ah[3], al[3];
#pragma unroll
        for (int s = 0; s < 3; s++) {
            int rw = row0 + s * 16 + lr;
            int rc = (rw < n) ? rw : (n - 1);
            const float* ap = agg + (size_t)rc * DFEAT + k0;
            float v[8];
            *(float4*)(v)     = *(const float4*)(ap);
            *(float4*)(v + 4) = *(const float4*)(ap + 4);
#pragma unroll
            for (int j = 0; j < 8; j++) {
                float a = fmaxf(v[j] + bb[j], 0.f);
                unsigned hb = bf16_rtn(a);
                ah[s][j] = (short)hb;
                al[s][j] = (short)bf16_rtn(a - bf16f(hb));
            }
        }
#pragma unroll
        for (int ct = 0; ct < 8; ct++) {
            int brow = ct * 16 + lr;
            int byte = (brow << 8) + ((k0 * 2) ^ ((brow & 7) << 4));
            bf16x8 bh = *(const bf16x8*)((const char*)Bh + byte);
            bf16x8 bl = *(const bf16x8*)((const char*)Bl + byte);
#pragma unroll
            for (int s = 0; s < 3; s++) {
                acc[s][ct] = __builtin_amdgcn_mfma_f32_16x16x32_bf16(ah[s], bh, acc[s][ct], 0, 0, 0);
                acc[s][ct] = __builtin_amdgcn_mfma_f32_16x16x32_bf16(al[s], bh, acc[s][ct], 0, 0, 0);
                acc[s][ct] = __builtin_amdgcn_mfma_f32_16x16x32_bf16(ah[s], bl, acc[s][ct], 0, 0, 0);
            }
        }
    }

    // epilogue: + x residual (f32 exact), relu, store
#pragma unroll
    for (int s = 0; s < 3; s++) {
#pragma unroll
        for (int r = 0; r < 4; r++) {
            int rw = row0 + s * 16 + lq * 4 + r;
            if (rw < n) {
#pragma unroll
                for (int ct = 0; ct < 8; ct++) {
                    int col = ct * 16 + lr;
                    float v = acc[s][ct][r] + x[(size_t)rw * DFEAT + col];
                    out[(size_t)rw * DFEAT + col] = fmaxf(v, 0.f);
                }
            }
        }
    }
}

extern "C" void kernel_launch(void* const* d_in, const int* in_sizes, int n_in,
                              void* d_out, int out_size, void* d_ws, size_t ws_size,
                              hipStream_t stream) {
    const float* x    = (const float*)d_in[0];
    const int*   ei   = (const int*)d_in[1];
    const float* Wg   = (const float*)d_in[2];
    const float* bg   = (const float*)d_in[3];
    const float* Wln  = (const float*)d_in[4];
    float*       out  = (float*)d_out;

    int n = in_sizes[0] / DFEAT;      // 100000
    int E = in_sizes[1] / 2;          // 1600000
    int K = (n + PNODES - 1) >> PSH;  // 196 partitions

    size_t off = 0;
    auto take = [&](size_t bytes) {
        void* p = (char*)d_ws + off;
        off += (bytes + 255) & ~(size_t)255;
        return p;
    };
    int*      gcur  = (int*)take((size_t)PMAX * 4);
    int*      spc   = (int*)take(256);
    int*      cnt   = (int*)take((size_t)n * 4);
    float*    dinv  = (float*)take((size_t)n * 4);
    int2*     spill = (int2*)take((size_t)SPILLMAX * 8);
    unsigned* rec   = (unsigned*)take((size_t)K * REGCAP * 4);
    int*      buf   = (int*)take((size_t)n * CAP * 4);
    unsigned* h     = (unsigned*)take((size_t)n * 64 * 4);   // bf16x2 packed

    int gblocks = (n + GROWS - 1) / GROWS;   // 521

    hipMemsetAsync(gcur, 0, (size_t)PMAX * 4, stream);
    hipMemsetAsync(spc, 0, 4, stream);
    partA_kernel<<<(E + CHUNK - 1) / CHUNK, 256, 0, stream>>>(ei, rec, gcur, spill, spc, E);
    partB_kernel<<<K, 256, 0, stream>>>(rec, gcur, buf, cnt, dinv, spill, spc, n);
    gemm1_kernel<<<gblocks, 256, 0, stream>>>(x, Wg, dinv, h, n);
    propagate_kernel<<<(n + 3) / 4, 256, 0, stream>>>(h, buf, cnt, dinv, out, n);
    spill_kernel<<<SPILLMAX / 4, 256, 0, stream>>>(h, spill, spc, dinv, out);
    gemm2_kernel<<<gblocks, 256, 0, stream>>>(out, Wln, bg, x, out, n);
}